// Round 1
// baseline (548.527 us; speedup 1.0000x reference)
//
#include <hip/hip_runtime.h>

typedef _Float16 f16;
typedef __attribute__((ext_vector_type(8))) _Float16 f16x8;
typedef __attribute__((ext_vector_type(4))) _Float16 f16x4;
typedef __attribute__((ext_vector_type(4))) float    f32x4;

#define MFMA_F16(a,b,c) __builtin_amdgcn_mfma_f32_16x16x32_f16((a),(b),(c),0,0,0)

// problem constants
constexpr int Bc   = 4;
constexpr int Sc   = 2048;
constexpr int Hc   = 12;
constexpr int Dc   = 100;
constexpr int HIDc = 1200;
constexpr int BH   = Bc * Hc;    // 48
constexpr int DP   = 128;        // padded head dim (QK K-dim must be 0-padded)
constexpr int LDK  = 1216;       // padded inner dim for x16/w16 (1200 -> 38*32)
constexpr int NWP  = 1280;       // padded row count for w16 (N-tile overrun)

// ---------------- fp32 -> fp16 convert with zero padding ----------------
__global__ void cvt_pad_kernel(const float* __restrict__ src, f16* __restrict__ dst,
                               int srcR, int srcC, int dstC, int total) {
    int i = blockIdx.x * 256 + threadIdx.x;
    if (i >= total) return;
    int r = i / dstC, c = i - r * dstC;
    float v = (r < srcR && c < srcC) ? src[r * srcC + c] : 0.f;
    dst[i] = (f16)v;
}

// zero the d in [100,128) pads of Q (s-major), K (s-major) and V^T (d-major)
__global__ void pad_bufs_kernel(f16* __restrict__ q, f16* __restrict__ k, f16* __restrict__ vt) {
    int i = blockIdx.x * 256 + threadIdx.x;
    constexpr int PADW = DP - Dc;              // 28
    if (i >= BH * Sc * PADW) return;
    int dd = i % PADW;
    int rs = i / PADW;                          // bh*S + s
    int d  = Dc + dd;
    q[rs * DP + d] = (f16)0.f;
    k[rs * DP + d] = (f16)0.f;
    int bh = rs >> 11, s = rs & (Sc - 1);
    vt[(bh * DP + d) * Sc + s] = (f16)0.f;
}

// ---------------- B^T GEMM: C[m,n] = sum_k A[m,k]*B[n,k], f16 in / f32 acc --
// mode 0: store f16 scatter to (b,h,s,d) padded-128 layout   (Q, K)
// mode 2: store f16 to transposed (b,h,d,s) layout, 4-s packed (V)
// mode 3: store f32 row-major M x 1200                        (final out)
__launch_bounds__(256)
__global__ void gemm_bt_kernel(const f16* __restrict__ A, int lda,
                               const f16* __restrict__ Bm,
                               f16* __restrict__ outQK,
                               f16* __restrict__ outVT,
                               float* __restrict__ outF,
                               int K, int mode) {
    __shared__ f16 As[128][72];   // 64 k + 8 pad (stride 144B: 16B-aligned, 2-way banks)
    __shared__ f16 Bs[128][72];

    const int tid  = threadIdx.x;
    const int lane = tid & 63, wave = tid >> 6;
    const int wm = wave >> 1, wn = wave & 1;     // 2x2 wave grid, 64x64 per wave
    const int n15 = lane & 15, g = lane >> 4;
    const int brow = blockIdx.x * 128;
    const int bcol = blockIdx.y * 128;

    f32x4 acc[4][4];
#pragma unroll
    for (int i = 0; i < 4; ++i)
#pragma unroll
        for (int j = 0; j < 4; ++j)
            acc[i][j] = (f32x4){0.f, 0.f, 0.f, 0.f};

    const int nkt = (K + 63) >> 6;               // 19 for K=1200
    for (int kt = 0; kt < nkt; ++kt) {
        const int k0 = kt << 6;
        __syncthreads();
        // stage 128x64 f16 tiles of A and B (reg-staged; K-tail zero-filled)
#pragma unroll
        for (int j = 0; j < 4; ++j) {
            const int c   = j * 256 + tid;       // 1024 chunks of 8 f16
            const int row = c >> 3;
            const int c8  = (c & 7) * 8;
            f16x8 va, vb;
            if (k0 + c8 < K) {                   // K % 8 == 0 -> chunk-granular
                va = *(const f16x8*)(A  + (brow + row) * lda + k0 + c8);
                vb = *(const f16x8*)(Bm + (bcol + row) * LDK + k0 + c8);
            } else {
#pragma unroll
                for (int e = 0; e < 8; ++e) { va[e] = (f16)0.f; vb[e] = (f16)0.f; }
            }
            *(f16x8*)&As[row][c8] = va;
            *(f16x8*)&Bs[row][c8] = vb;
        }
        __syncthreads();
#pragma unroll
        for (int kc = 0; kc < 2; ++kc) {
            f16x8 af[4], bf[4];
#pragma unroll
            for (int i = 0; i < 4; ++i)
                af[i] = *(const f16x8*)&As[wm * 64 + i * 16 + n15][kc * 32 + g * 8];
#pragma unroll
            for (int i = 0; i < 4; ++i)
                bf[i] = *(const f16x8*)&Bs[wn * 64 + i * 16 + n15][kc * 32 + g * 8];
#pragma unroll
            for (int mi = 0; mi < 4; ++mi)
#pragma unroll
                for (int ni = 0; ni < 4; ++ni)
                    acc[mi][ni] = MFMA_F16(af[mi], bf[ni], acc[mi][ni]);
        }
    }

    // epilogue — C/D frag: row = 4*g + r, col = n15 (guide §3, m89-verified)
#pragma unroll
    for (int mi = 0; mi < 4; ++mi) {
        const int m0 = brow + wm * 64 + mi * 16 + g * 4;   // 4-aligned -> same b for r=0..3
        const int b  = m0 >> 11;
        const int s0 = m0 & (Sc - 1);
#pragma unroll
        for (int ni = 0; ni < 4; ++ni) {
            const int n = bcol + wn * 64 + ni * 16 + n15;
            if (n >= HIDc) continue;
            if (mode == 0) {
                const int h = n / 100, d = n - h * 100;
                f16* dst = outQK + ((b * Hc + h) * Sc + s0) * DP + d;
#pragma unroll
                for (int r = 0; r < 4; ++r)
                    dst[r * DP] = (f16)acc[mi][ni][r];
            } else if (mode == 2) {
                const int h = n / 100, d = n - h * 100;
                f16x4 pk;
#pragma unroll
                for (int r = 0; r < 4; ++r) pk[r] = (f16)acc[mi][ni][r];
                *(f16x4*)(outVT + ((b * Hc + h) * DP + d) * Sc + s0) = pk;
            } else {
                float* dst = outF + m0 * HIDc + n;
#pragma unroll
                for (int r = 0; r < 4; ++r)
                    dst[r * HIDc] = acc[mi][ni][r];
            }
        }
    }
}

// ---------------- fused flash attention ----------------
// grid (16, 48): blockIdx.x = q-tile of 128 rows, blockIdx.y = (b,h)
// 4 waves/block, each owns 32 q-rows. Online softmax in fp32.
__launch_bounds__(256)
__global__ void attn_kernel(const f16* __restrict__ Qp, const f16* __restrict__ Kp,
                            const f16* __restrict__ Vt, const float* __restrict__ alibi,
                            const float* __restrict__ amask, const int* __restrict__ lidx,
                            f16* __restrict__ outp) {
    __shared__ f16 Kl[64][136];        // keys: [t][d], stride 272B (17x16B, 2-way banks)
    __shared__ f16 Vl[128][72];        // V^T:  [d][t], stride 144B
    __shared__ f16 Pl[4][32][72];      // per-wave P re-layout buffer

    const int tid  = threadIdx.x;
    const int lane = tid & 63, wave = tid >> 6;
    const int n15 = lane & 15, g = lane >> 4;
    const int bh = blockIdx.y;
    const int b  = bh / Hc;
    const int qr0 = blockIdx.x * 128 + wave * 32;

    const float inv_l1 = 1.f / (float)(lidx[0] + 1);
    const float scale  = 10.f * inv_l1;          // sqrt(100)/(layer+1)

    // hoist Q (32 rows x 128 d) into registers
    const f16* Qb = Qp + (bh * Sc + qr0) * DP;
    f16x8 qreg[2][4];
#pragma unroll
    for (int mf = 0; mf < 2; ++mf)
#pragma unroll
        for (int kc = 0; kc < 4; ++kc)
            qreg[mf][kc] = *(const f16x8*)(Qb + (mf * 16 + n15) * DP + kc * 32 + g * 8);

    float m_run[2][4], l_run[2][4];
    f32x4 accO[2][7];                  // d up to 112 covers the 100 real dims
#pragma unroll
    for (int mf = 0; mf < 2; ++mf) {
#pragma unroll
        for (int r = 0; r < 4; ++r) { m_run[mf][r] = -1e30f; l_run[mf][r] = 0.f; }
#pragma unroll
        for (int df = 0; df < 7; ++df) accO[mf][df] = (f32x4){0.f, 0.f, 0.f, 0.f};
    }

    for (int tile = 0; tile < Sc / 64; ++tile) {
        const int t0 = tile * 64;
        __syncthreads();
        // stage K tile (64 x 128) and V^T tile (128 x 64), both coalesced
#pragma unroll
        for (int j = 0; j < 4; ++j) {
            const int c = j * 256 + tid;
            const int krow = c >> 4, kc8 = (c & 15) * 8;
            f16x8 kv = *(const f16x8*)(Kp + (bh * Sc + t0 + krow) * DP + kc8);
            *(f16x8*)&Kl[krow][kc8] = kv;
            const int vrow = c >> 3, vc8 = (c & 7) * 8;
            f16x8 vv = *(const f16x8*)(Vt + (bh * DP + vrow) * Sc + t0 + vc8);
            *(f16x8*)&Vl[vrow][vc8] = vv;
        }
        __syncthreads();

        // S = Q K^T  (per wave: 32 x 64, K-dim 128)
        f32x4 sc[2][4];
#pragma unroll
        for (int mf = 0; mf < 2; ++mf)
#pragma unroll
            for (int nf = 0; nf < 4; ++nf)
                sc[mf][nf] = (f32x4){0.f, 0.f, 0.f, 0.f};
#pragma unroll
        for (int kc = 0; kc < 4; ++kc) {
            f16x8 bf[4];
#pragma unroll
            for (int nf = 0; nf < 4; ++nf)
                bf[nf] = *(const f16x8*)&Kl[nf * 16 + n15][kc * 32 + g * 8];
#pragma unroll
            for (int mf = 0; mf < 2; ++mf)
#pragma unroll
                for (int nf = 0; nf < 4; ++nf)
                    sc[mf][nf] = MFMA_F16(qreg[mf][kc], bf[nf], sc[mf][nf]);
        }

        // bias(t) = alibi/(L+1) + mask  (column = t0 + nf*16 + n15)
        float bias[4];
#pragma unroll
        for (int nf = 0; nf < 4; ++nf) {
            const int t = t0 + nf * 16 + n15;
            bias[nf] = alibi[bh * Sc + t] * inv_l1 + amask[b * Sc + t];
        }

        // online softmax; row (mf,r) lives in 16 consecutive lanes (same g)
#pragma unroll
        for (int mf = 0; mf < 2; ++mf) {
            float tmax[4] = {-1e30f, -1e30f, -1e30f, -1e30f};
#pragma unroll
            for (int nf = 0; nf < 4; ++nf)
#pragma unroll
                for (int r = 0; r < 4; ++r) {
                    float v = sc[mf][nf][r] * scale + bias[nf];
                    sc[mf][nf][r] = v;
                    tmax[r] = fmaxf(tmax[r], v);
                }
#pragma unroll
            for (int off = 1; off < 16; off <<= 1)
#pragma unroll
                for (int r = 0; r < 4; ++r)
                    tmax[r] = fmaxf(tmax[r], __shfl_xor(tmax[r], off));
#pragma unroll
            for (int r = 0; r < 4; ++r) {
                const float mn = fmaxf(m_run[mf][r], tmax[r]);
                const float al = __expf(m_run[mf][r] - mn);
                m_run[mf][r] = mn;
                l_run[mf][r] *= al;
#pragma unroll
                for (int df = 0; df < 7; ++df)
                    accO[mf][df][r] *= al;
            }
            float ps[4] = {0.f, 0.f, 0.f, 0.f};
#pragma unroll
            for (int nf = 0; nf < 4; ++nf)
#pragma unroll
                for (int r = 0; r < 4; ++r) {
                    const float p = __expf(sc[mf][nf][r] - m_run[mf][r]);
                    sc[mf][nf][r] = p;
                    ps[r] += p;
                }
#pragma unroll
            for (int off = 1; off < 16; off <<= 1)
#pragma unroll
                for (int r = 0; r < 4; ++r)
                    ps[r] += __shfl_xor(ps[r], off);
#pragma unroll
            for (int r = 0; r < 4; ++r)
                l_run[mf][r] += ps[r];
            // P -> per-wave LDS (fp16) for the PV A-operand re-layout
#pragma unroll
            for (int nf = 0; nf < 4; ++nf)
#pragma unroll
                for (int r = 0; r < 4; ++r)
                    Pl[wave][mf * 16 + g * 4 + r][nf * 16 + n15] = (f16)sc[mf][nf][r];
        }
        __syncthreads();

        // O += P V   (per wave: 32 x 112, K-dim 64)
#pragma unroll
        for (int kc = 0; kc < 2; ++kc) {
            f16x8 pa[2];
#pragma unroll
            for (int mf = 0; mf < 2; ++mf)
                pa[mf] = *(const f16x8*)&Pl[wave][mf * 16 + n15][kc * 32 + g * 8];
#pragma unroll
            for (int df = 0; df < 7; ++df) {
                const f16x8 vb = *(const f16x8*)&Vl[df * 16 + n15][kc * 32 + g * 8];
#pragma unroll
                for (int mf = 0; mf < 2; ++mf)
                    accO[mf][df] = MFMA_F16(pa[mf], vb, accO[mf][df]);
            }
        }
    }

    // write comb in natural (b,h,s,d<100) C-order: final GEMM reads it linearly
#pragma unroll
    for (int mf = 0; mf < 2; ++mf) {
#pragma unroll
        for (int r = 0; r < 4; ++r) {
            const float rl = 1.f / l_run[mf][r];
            const int qrow = qr0 + mf * 16 + g * 4 + r;
#pragma unroll
            for (int df = 0; df < 7; ++df) {
                const int d = df * 16 + n15;
                if (d < Dc)
                    outp[(bh * Sc + qrow) * Dc + d] = (f16)(accO[mf][df][r] * rl);
            }
        }
    }
}

// ---------------- launcher ----------------
extern "C" void kernel_launch(void* const* d_in, const int* in_sizes, int n_in,
                              void* d_out, int out_size, void* d_ws, size_t ws_size,
                              hipStream_t stream) {
    const float* x     = (const float*)d_in[0];
    const float* alibi = (const float*)d_in[1];
    const float* amask = (const float*)d_in[2];
    const float* wq    = (const float*)d_in[3];
    const float* wk    = (const float*)d_in[4];
    const float* wv    = (const float*)d_in[5];
    const float* wo    = (const float*)d_in[6];
    const int*   lidx  = (const int*)d_in[7];
    float* out = (float*)d_out;

    char* p = (char*)d_ws;
    auto carve = [&](size_t bytes) {
        char* q = p;
        p += (bytes + 255) & ~size_t(255);
        return q;
    };
    f16* x16  = (f16*)carve((size_t)(Bc * Sc) * LDK * 2);        // 8192 x 1216
    f16* wq16 = (f16*)carve((size_t)NWP * LDK * 2);              // 1280 x 1216
    f16* wk16 = (f16*)carve((size_t)NWP * LDK * 2);
    f16* wv16 = (f16*)carve((size_t)NWP * LDK * 2);
    f16* wo16 = (f16*)carve((size_t)NWP * LDK * 2);
    f16* Qp   = (f16*)carve((size_t)BH * Sc * DP * 2);           // (bh,s,128)
    f16* Kp   = (f16*)carve((size_t)BH * Sc * DP * 2);
    f16* Vtp  = (f16*)carve((size_t)BH * DP * Sc * 2);           // (bh,128,s)
    f16* comb = (f16*)carve((size_t)BH * Sc * Dc * 2);           // (bh,s,100)

    // 1) fp16 conversions (+ zero pads)
    {
        int total = Bc * Sc * LDK;
        cvt_pad_kernel<<<(total + 255) / 256, 256, 0, stream>>>(x, x16, Bc * Sc, HIDc, LDK, total);
    }
    {
        int total = NWP * LDK;
        int nb = (total + 255) / 256;
        cvt_pad_kernel<<<nb, 256, 0, stream>>>(wq, wq16, HIDc, HIDc, LDK, total);
        cvt_pad_kernel<<<nb, 256, 0, stream>>>(wk, wk16, HIDc, HIDc, LDK, total);
        cvt_pad_kernel<<<nb, 256, 0, stream>>>(wv, wv16, HIDc, HIDc, LDK, total);
        cvt_pad_kernel<<<nb, 256, 0, stream>>>(wo, wo16, HIDc, HIDc, LDK, total);
    }
    // 2) zero the d-pads of Q/K/V^T (must be zero every call: K feeds QK^T K-dim)
    {
        int total = BH * Sc * (DP - Dc);
        pad_bufs_kernel<<<(total + 255) / 256, 256, 0, stream>>>(Qp, Kp, Vtp);
    }
    // 3) projections
    dim3 gg(64, 10);
    gemm_bt_kernel<<<gg, 256, 0, stream>>>(x16, LDK, wq16, Qp, nullptr, nullptr, HIDc, 0);
    gemm_bt_kernel<<<gg, 256, 0, stream>>>(x16, LDK, wk16, Kp, nullptr, nullptr, HIDc, 0);
    gemm_bt_kernel<<<gg, 256, 0, stream>>>(x16, LDK, wv16, nullptr, Vtp, nullptr, HIDc, 2);
    // 4) fused attention
    attn_kernel<<<dim3(Sc / 128, BH), 256, 0, stream>>>(Qp, Kp, Vtp, alibi, amask, lidx, comb);
    // 5) output projection (reads comb linearly as 8192 x 1200)
    gemm_bt_kernel<<<gg, 256, 0, stream>>>(comb, HIDc, wo16, nullptr, nullptr, out, HIDc, 3);
}

// Round 2
// 366.212 us; speedup vs baseline: 1.4978x; 1.4978x over previous
//
#include <hip/hip_runtime.h>

typedef _Float16 f16;
typedef __attribute__((ext_vector_type(8))) _Float16 f16x8;
typedef __attribute__((ext_vector_type(4))) _Float16 f16x4;
typedef __attribute__((ext_vector_type(4))) float    f32x4;

#define MFMA_F16(a,b,c) __builtin_amdgcn_mfma_f32_16x16x32_f16((a),(b),(c),0,0,0)

// problem constants
constexpr int Bc   = 4;
constexpr int Sc   = 2048;
constexpr int Hc   = 12;
constexpr int Dc   = 100;
constexpr int HIDc = 1200;
constexpr int BH   = Bc * Hc;    // 48
constexpr int DP   = 128;        // padded head dim (dim 100 carries the bias trick)
constexpr int LDK  = 1216;       // padded inner dim for x16/w16 (1200 -> 38*32)
constexpr int NWP  = 1280;       // padded row count for w16 (N-tile overrun)

// ---------------- fp32 -> fp16 convert with zero padding (x4 vectorized) ----
__global__ void cvt_pad4_kernel(const float* __restrict__ src, f16* __restrict__ dst,
                                int srcR, int srcC, int dstC, int total4) {
    int i = blockIdx.x * 256 + threadIdx.x;
    if (i >= total4) return;
    int idx = i * 4;
    int r = idx / dstC, c = idx - r * dstC;     // dstC % 4 == 0 -> no row straddle
    f16x4 o;
    if (r < srcR && c + 3 < srcC) {
        float4 v = *(const float4*)(src + r * srcC + c);
        o[0] = (f16)v.x; o[1] = (f16)v.y; o[2] = (f16)v.z; o[3] = (f16)v.w;
    } else {
#pragma unroll
        for (int e = 0; e < 4; ++e) {
            float vv = (r < srcR && c + e < srcC) ? src[r * srcC + c + e] : 0.f;
            o[e] = (f16)vv;
        }
    }
    *(f16x4*)(dst + idx) = o;
}

// pads of Q/K/V^T in d=[100,128).  d==100 carries the softmax bias:
//   Q[s,100]=1 (gets scaled by 10*log2e/(L+1) in attn), K[t,100]=alibi/10+mask*(L+1)/10
//   so QK^T emits log2-domain logits with alibi+mask already added.
__global__ void pad_bufs_kernel(f16* __restrict__ q, f16* __restrict__ k, f16* __restrict__ vt,
                                const float* __restrict__ alibi, const float* __restrict__ amask,
                                const int* __restrict__ lidx) {
    int i = blockIdx.x * 256 + threadIdx.x;
    constexpr int PADW = DP - Dc;              // 28
    if (i >= BH * Sc * PADW) return;
    int dd = i % PADW;
    int rs = i / PADW;                          // bh*S + t
    int d  = Dc + dd;
    int bh = rs >> 11, t = rs & (Sc - 1);
    int b  = bh / Hc;
    if (d == Dc) {
        float bias = alibi[rs] * 0.1f + amask[b * Sc + t] * ((float)(lidx[0] + 1) * 0.1f);
        q[rs * DP + d] = (f16)1.0f;
        k[rs * DP + d] = (f16)bias;
    } else {
        q[rs * DP + d] = (f16)0.f;
        k[rs * DP + d] = (f16)0.f;
    }
    vt[(bh * DP + d) * Sc + t] = (f16)0.f;
}

// ---------------- B^T GEMM: C[m,n] = sum_k A[m,k]*B[n,k], f16 in / f32 acc --
// mode 0: store f16 scatter to (b,h,s,d) padded-128 layout   (Q, K)
// mode 2: store f16 to transposed (b,h,d,s) layout, 4-s packed (V)
// mode 3: store f32 row-major M x 1200                        (final out)
__launch_bounds__(256)
__global__ void gemm_bt_kernel(const f16* __restrict__ A, int lda,
                               const f16* __restrict__ Bm,
                               f16* __restrict__ outQK,
                               f16* __restrict__ outVT,
                               float* __restrict__ outF,
                               int K, int mode) {
    __shared__ f16 As[128][72];   // 64 k + 8 pad (stride 144B: 16B-aligned, 2-way banks)
    __shared__ f16 Bs[128][72];

    const int tid  = threadIdx.x;
    const int lane = tid & 63, wave = tid >> 6;
    const int wm = wave >> 1, wn = wave & 1;     // 2x2 wave grid, 64x64 per wave
    const int n15 = lane & 15, g = lane >> 4;
    const int brow = blockIdx.x * 128;
    const int bcol = blockIdx.y * 128;

    f32x4 acc[4][4];
#pragma unroll
    for (int i = 0; i < 4; ++i)
#pragma unroll
        for (int j = 0; j < 4; ++j)
            acc[i][j] = (f32x4){0.f, 0.f, 0.f, 0.f};

    const int nkt = (K + 63) >> 6;               // 19 for K=1200
    for (int kt = 0; kt < nkt; ++kt) {
        const int k0 = kt << 6;
        __syncthreads();
        // stage 128x64 f16 tiles of A and B (reg-staged; K-tail zero-filled)
#pragma unroll
        for (int j = 0; j < 4; ++j) {
            const int c   = j * 256 + tid;       // 1024 chunks of 8 f16
            const int row = c >> 3;
            const int c8  = (c & 7) * 8;
            f16x8 va, vb;
            if (k0 + c8 < K) {                   // K % 8 == 0 -> chunk-granular
                va = *(const f16x8*)(A  + (brow + row) * lda + k0 + c8);
                vb = *(const f16x8*)(Bm + (bcol + row) * LDK + k0 + c8);
            } else {
#pragma unroll
                for (int e = 0; e < 8; ++e) { va[e] = (f16)0.f; vb[e] = (f16)0.f; }
            }
            *(f16x8*)&As[row][c8] = va;
            *(f16x8*)&Bs[row][c8] = vb;
        }
        __syncthreads();
#pragma unroll
        for (int kc = 0; kc < 2; ++kc) {
            f16x8 af[4], bf[4];
#pragma unroll
            for (int i = 0; i < 4; ++i)
                af[i] = *(const f16x8*)&As[wm * 64 + i * 16 + n15][kc * 32 + g * 8];
#pragma unroll
            for (int i = 0; i < 4; ++i)
                bf[i] = *(const f16x8*)&Bs[wn * 64 + i * 16 + n15][kc * 32 + g * 8];
#pragma unroll
            for (int mi = 0; mi < 4; ++mi)
#pragma unroll
                for (int ni = 0; ni < 4; ++ni)
                    acc[mi][ni] = MFMA_F16(af[mi], bf[ni], acc[mi][ni]);
        }
    }

    // epilogue — C/D frag: row = 4*g + r, col = n15
#pragma unroll
    for (int mi = 0; mi < 4; ++mi) {
        const int m0 = brow + wm * 64 + mi * 16 + g * 4;   // 4-aligned -> same b for r=0..3
        const int b  = m0 >> 11;
        const int s0 = m0 & (Sc - 1);
#pragma unroll
        for (int ni = 0; ni < 4; ++ni) {
            const int n = bcol + wn * 64 + ni * 16 + n15;
            if (n >= HIDc) continue;
            if (mode == 0) {
                const int h = n / 100, d = n - h * 100;
                f16* dst = outQK + ((b * Hc + h) * Sc + s0) * DP + d;
#pragma unroll
                for (int r = 0; r < 4; ++r)
                    dst[r * DP] = (f16)acc[mi][ni][r];
            } else if (mode == 2) {
                const int h = n / 100, d = n - h * 100;
                f16x4 pk;
#pragma unroll
                for (int r = 0; r < 4; ++r) pk[r] = (f16)acc[mi][ni][r];
                *(f16x4*)(outVT + ((b * Hc + h) * DP + d) * Sc + s0) = pk;
            } else {
                float* dst = outF + m0 * HIDc + n;
#pragma unroll
                for (int r = 0; r < 4; ++r)
                    dst[r * HIDc] = acc[mi][ni][r];
            }
        }
    }
}

// ---------------- fused flash attention (swapped-operand, log2 domain) -------
// grid (16, 48): blockIdx.x = q-tile of 128 rows, blockIdx.y = (b,h)
// 4 waves/block, each owns 32 q-rows. S^T = mfma(K,Q), O^T = mfma(V^T,P^T):
// softmax state is lane-local (q = lane&15 per q-frag).
__launch_bounds__(256)
__global__ void attn_kernel(const f16* __restrict__ Qp, const f16* __restrict__ Kp,
                            const f16* __restrict__ Vt, const int* __restrict__ lidx,
                            f16* __restrict__ outp) {
    __shared__ f16 Kl[64][136];        // keys: [t][d], stride 272B (2-way banks)
    __shared__ f16 Vl[128][72];        // V^T:  [d][t], stride 144B
    __shared__ f16 Pl[4][32][72];      // per-wave P: [q][t]

    const int tid  = threadIdx.x;
    const int lane = tid & 63, wave = tid >> 6;
    const int n15 = lane & 15, g = lane >> 4;
    const int bh = blockIdx.y;
    const int qr0 = blockIdx.x * 128 + wave * 32;

    // log2-domain scale: exp(s*10/(L+1)) == exp2(s*10*log2e/(L+1))
    const float scale = 10.f * 1.44269504f / (float)(lidx[0] + 1);

    // hoist Q (32 rows x 128 d) into registers, pre-scaled (f32 mul per elem)
    const f16* Qb = Qp + (bh * Sc + qr0) * DP;
    f16x8 qreg[2][4];
#pragma unroll
    for (int qf = 0; qf < 2; ++qf)
#pragma unroll
        for (int kc = 0; kc < 4; ++kc) {
            f16x8 v = *(const f16x8*)(Qb + (qf * 16 + n15) * DP + kc * 32 + g * 8);
#pragma unroll
            for (int e = 0; e < 8; ++e)
                v[e] = (f16)((float)v[e] * scale);
            qreg[qf][kc] = v;
        }

    float m_run[2] = {-1e30f, -1e30f};
    float l_run[2] = {0.f, 0.f};
    f32x4 accO[2][7];                  // O^T: d = df*16 + g*4 + r, q = n15
#pragma unroll
    for (int qf = 0; qf < 2; ++qf)
#pragma unroll
        for (int df = 0; df < 7; ++df)
            accO[qf][df] = (f32x4){0.f, 0.f, 0.f, 0.f};

    for (int tile = 0; tile < Sc / 64; ++tile) {
        const int t0 = tile * 64;
        __syncthreads();
        // stage K tile (64 x 128) and V^T tile (128 x 64), both coalesced
#pragma unroll
        for (int j = 0; j < 4; ++j) {
            const int c = j * 256 + tid;
            const int krow = c >> 4, kc8 = (c & 15) * 8;
            f16x8 kv = *(const f16x8*)(Kp + (bh * Sc + t0 + krow) * DP + kc8);
            *(f16x8*)&Kl[krow][kc8] = kv;
            const int vrow = c >> 3, vc8 = (c & 7) * 8;
            f16x8 vv = *(const f16x8*)(Vt + (bh * DP + vrow) * Sc + t0 + vc8);
            *(f16x8*)&Vl[vrow][vc8] = vv;
        }
        __syncthreads();

        // S^T = K Q^T per wave: sc[qf][tf], lane holds q=n15, t=tf*16+g*4+r
        f32x4 sc[2][4];
#pragma unroll
        for (int qf = 0; qf < 2; ++qf)
#pragma unroll
            for (int tf = 0; tf < 4; ++tf)
                sc[qf][tf] = (f32x4){0.f, 0.f, 0.f, 0.f};
#pragma unroll
        for (int kc = 0; kc < 4; ++kc) {
            f16x8 kf[4];
#pragma unroll
            for (int tf = 0; tf < 4; ++tf)
                kf[tf] = *(const f16x8*)&Kl[tf * 16 + n15][kc * 32 + g * 8];
#pragma unroll
            for (int qf = 0; qf < 2; ++qf)
#pragma unroll
                for (int tf = 0; tf < 4; ++tf)
                    sc[qf][tf] = MFMA_F16(kf[tf], qreg[qf][kc], sc[qf][tf]);
        }

        // tile max per q (lane-local 16 vals + 2 shfl across g-groups)
        float tmax[2];
#pragma unroll
        for (int qf = 0; qf < 2; ++qf) {
            float m0 = fmaxf(fmaxf(sc[qf][0][0], sc[qf][0][1]), fmaxf(sc[qf][0][2], sc[qf][0][3]));
#pragma unroll
            for (int tf = 1; tf < 4; ++tf)
                m0 = fmaxf(m0, fmaxf(fmaxf(sc[qf][tf][0], sc[qf][tf][1]),
                                     fmaxf(sc[qf][tf][2], sc[qf][tf][3])));
            m0 = fmaxf(m0, __shfl_xor(m0, 16));
            m0 = fmaxf(m0, __shfl_xor(m0, 32));
            tmax[qf] = m0;
        }

        // defer-max (T13): rescale only when a q exceeds its running max by >8
        if (__any((tmax[0] > m_run[0] + 8.f) || (tmax[1] > m_run[1] + 8.f))) {
#pragma unroll
            for (int qf = 0; qf < 2; ++qf) {
                const float mn = fmaxf(m_run[qf], tmax[qf]);
                const float al = exp2f(m_run[qf] - mn);
                m_run[qf] = mn;
                l_run[qf] *= al;
#pragma unroll
                for (int df = 0; df < 7; ++df) {
                    accO[qf][df][0] *= al; accO[qf][df][1] *= al;
                    accO[qf][df][2] *= al; accO[qf][df][3] *= al;
                }
            }
        }

        // P = exp2(s - m), row-sum, pack to LDS (b64 per (qf,tf))
#pragma unroll
        for (int qf = 0; qf < 2; ++qf) {
            float ps = 0.f;
#pragma unroll
            for (int tf = 0; tf < 4; ++tf) {
                f16x4 pk;
#pragma unroll
                for (int r = 0; r < 4; ++r) {
                    const float p = exp2f(sc[qf][tf][r] - m_run[qf]);
                    ps += p;
                    pk[r] = (f16)p;
                }
                *(f16x4*)&Pl[wave][qf * 16 + n15][tf * 16 + g * 4] = pk;
            }
            ps += __shfl_xor(ps, 16);
            ps += __shfl_xor(ps, 32);
            l_run[qf] += ps;
        }

        // O^T += V^T P^T  per wave: accO[qf][df] (no barrier: Pl is per-wave)
#pragma unroll
        for (int kc = 0; kc < 2; ++kc) {
            f16x8 pa[2];
#pragma unroll
            for (int qf = 0; qf < 2; ++qf)
                pa[qf] = *(const f16x8*)&Pl[wave][qf * 16 + n15][kc * 32 + g * 8];
#pragma unroll
            for (int df = 0; df < 7; ++df) {
                const f16x8 vb = *(const f16x8*)&Vl[df * 16 + n15][kc * 32 + g * 8];
#pragma unroll
                for (int qf = 0; qf < 2; ++qf)
                    accO[qf][df] = MFMA_F16(vb, pa[qf], accO[qf][df]);
            }
        }
    }

    // epilogue: lane holds O[q=n15][d=df*16+g*4+r] -> packed f16x4 stores
#pragma unroll
    for (int qf = 0; qf < 2; ++qf) {
        const float rl = 1.f / l_run[qf];
        const int qrow = qr0 + qf * 16 + n15;
#pragma unroll
        for (int df = 0; df < 7; ++df) {
            const int d0 = df * 16 + g * 4;
            if (d0 < Dc) {
                f16x4 o;
#pragma unroll
                for (int r = 0; r < 4; ++r)
                    o[r] = (f16)(accO[qf][df][r] * rl);
                *(f16x4*)(outp + (bh * Sc + qrow) * Dc + d0) = o;
            }
        }
    }
}

// ---------------- launcher ----------------
extern "C" void kernel_launch(void* const* d_in, const int* in_sizes, int n_in,
                              void* d_out, int out_size, void* d_ws, size_t ws_size,
                              hipStream_t stream) {
    const float* x     = (const float*)d_in[0];
    const float* alibi = (const float*)d_in[1];
    const float* amask = (const float*)d_in[2];
    const float* wq    = (const float*)d_in[3];
    const float* wk    = (const float*)d_in[4];
    const float* wv    = (const float*)d_in[5];
    const float* wo    = (const float*)d_in[6];
    const int*   lidx  = (const int*)d_in[7];
    float* out = (float*)d_out;

    char* p = (char*)d_ws;
    auto carve = [&](size_t bytes) {
        char* q = p;
        p += (bytes + 255) & ~size_t(255);
        return q;
    };
    f16* x16  = (f16*)carve((size_t)(Bc * Sc) * LDK * 2);        // 8192 x 1216
    f16* wq16 = (f16*)carve((size_t)NWP * LDK * 2);              // 1280 x 1216
    f16* wk16 = (f16*)carve((size_t)NWP * LDK * 2);
    f16* wv16 = (f16*)carve((size_t)NWP * LDK * 2);
    f16* wo16 = (f16*)carve((size_t)NWP * LDK * 2);
    f16* Qp   = (f16*)carve((size_t)BH * Sc * DP * 2);           // (bh,s,128)
    f16* Kp   = (f16*)carve((size_t)BH * Sc * DP * 2);
    f16* Vtp  = (f16*)carve((size_t)BH * DP * Sc * 2);           // (bh,128,s)
    f16* comb = (f16*)carve((size_t)BH * Sc * Dc * 2);           // (bh,s,100)

    // 1) fp16 conversions (+ zero pads), x4-vectorized
    {
        int total4 = Bc * Sc * LDK / 4;
        cvt_pad4_kernel<<<(total4 + 255) / 256, 256, 0, stream>>>(x, x16, Bc * Sc, HIDc, LDK, total4);
    }
    {
        int total4 = NWP * LDK / 4;
        int nb = (total4 + 255) / 256;
        cvt_pad4_kernel<<<nb, 256, 0, stream>>>(wq, wq16, HIDc, HIDc, LDK, total4);
        cvt_pad4_kernel<<<nb, 256, 0, stream>>>(wk, wk16, HIDc, HIDc, LDK, total4);
        cvt_pad4_kernel<<<nb, 256, 0, stream>>>(wv, wv16, HIDc, HIDc, LDK, total4);
        cvt_pad4_kernel<<<nb, 256, 0, stream>>>(wo, wo16, HIDc, HIDc, LDK, total4);
    }
    // 2) pads of Q/K/V^T; d=100 carries the alibi+mask bias (log2-domain trick)
    {
        int total = BH * Sc * (DP - Dc);
        pad_bufs_kernel<<<(total + 255) / 256, 256, 0, stream>>>(Qp, Kp, Vtp, alibi, amask, lidx);
    }
    // 3) projections
    dim3 gg(64, 10);
    gemm_bt_kernel<<<gg, 256, 0, stream>>>(x16, LDK, wq16, Qp, nullptr, nullptr, HIDc, 0);
    gemm_bt_kernel<<<gg, 256, 0, stream>>>(x16, LDK, wk16, Kp, nullptr, nullptr, HIDc, 0);
    gemm_bt_kernel<<<gg, 256, 0, stream>>>(x16, LDK, wv16, nullptr, Vtp, nullptr, HIDc, 2);
    // 4) fused attention
    attn_kernel<<<dim3(Sc / 128, BH), 256, 0, stream>>>(Qp, Kp, Vtp, lidx, comb);
    // 5) output projection (reads comb linearly as 8192 x 1200)
    gemm_bt_kernel<<<gg, 256, 0, stream>>>(comb, HIDc, wo16, nullptr, nullptr, out, HIDc, 3);
}